// Round 7
// baseline (899.730 us; speedup 1.0000x reference)
//
#include <hip/hip_runtime.h>

#define D 128
#define DH 64  // D/2 (float2 pairs)

// ---------------------------------------------------------------------------
// CSR build: count -> scan (256 threads) -> fill (all bounds-checked)
// ---------------------------------------------------------------------------
__global__ __launch_bounds__(256) void count_kernel(
    const int* __restrict__ dst, int* __restrict__ cnt, int E, int N)
{
    int e = blockIdx.x * 256 + threadIdx.x;
    if (e >= E) return;
    int d = dst[e];
    if ((unsigned)d < (unsigned)N) atomicAdd(&cnt[d], 1);
}

__global__ __launch_bounds__(256) void scan_kernel(
    const int* __restrict__ cnt, int* __restrict__ rowptr,
    int* __restrict__ cursor, int N)
{
    __shared__ int lds[256];
    const int t  = threadIdx.x;
    const int CH = (N + 255) / 256;
    const int start = min(t * CH, N);
    const int end   = min(start + CH, N);
    int s = 0;
    for (int k = start; k < end; ++k) s += cnt[k];
    lds[t] = s;
    __syncthreads();
    for (int off = 1; off < 256; off <<= 1) {
        int v = (t >= off) ? lds[t - off] : 0;
        __syncthreads();
        lds[t] += v;
        __syncthreads();
    }
    int run = lds[t] - s;   // exclusive prefix of this chunk
    for (int k = start; k < end; ++k) {
        rowptr[k] = run; cursor[k] = run; run += cnt[k];
    }
    if (t == 255) rowptr[N] = lds[255];
}

__global__ __launch_bounds__(256) void fill_kernel(
    const int* __restrict__ src, const int* __restrict__ dst,
    int* __restrict__ cursor, int* __restrict__ esrc, int E, int N)
{
    int e = blockIdx.x * 256 + threadIdx.x;
    if (e >= E) return;
    int d = dst[e];
    if ((unsigned)d >= (unsigned)N) return;
    int p = atomicAdd(&cursor[d], 1);
    if ((unsigned)p < (unsigned)E) esrc[p] = src[e];
}

// ---------------------------------------------------------------------------
// Fused gather + GEMM + BN stats (all fp32).
// Block = 256: threads 0-127 -> row r (half 0), 128-255 -> row r+1 (half 1).
// Per row: h[j] = (1+eps)*x[i][j] + sum_nbr x[nbr][j] gathered straight into
// LDS; then hlin[i][j] = dot(h_row, W[j]) + b[j]; col sum/sumsq accumulated.
// hlin points at d_out (fp32, same element count) - filled fully here.
// ---------------------------------------------------------------------------
__global__ __launch_bounds__(256) void gemm_gather_stats_kernel(
    const float* __restrict__ x, const int* __restrict__ rowptr,
    const int* __restrict__ esrc, const float* __restrict__ W,
    const float* __restrict__ bb, const float* __restrict__ geps,
    float* hlin, float* __restrict__ stats, int N, int E)
{
    __shared__ __align__(16) float hrow[2][D];
    __shared__ float red[256];

    const int tid  = threadIdx.x;
    const int j    = tid & (D - 1);
    const int half = tid >> 7;

    // W row j -> 128 VGPRs (W is fp32 row-major [D][D]; row j = weights for out-col j)
    float w[D];
    {
        const float4* Wq = (const float4*)(W + j * D);
        #pragma unroll
        for (int q = 0; q < 32; ++q) {
            float4 u = Wq[q];
            w[4*q+0] = u.x; w[4*q+1] = u.y; w[4*q+2] = u.z; w[4*q+3] = u.w;
        }
    }
    const float eps1 = 1.0f + geps[0];
    const float bj   = bb[j];

    float psum = 0.0f, psq = 0.0f;
    const int row0 = blockIdx.x * 128;

    for (int it = 0; it < 64; ++it) {
        const int i = row0 + it * 2 + half;
        const bool valid = (i < N);
        if (valid) {
            int s0 = rowptr[i];
            int s1 = rowptr[i + 1];
            s0 = max(0, min(s0, E));       // any CSR bug stays finite
            s1 = max(s0, min(s1, E));
            float acc = eps1 * x[(long)i * D + j];
            for (int e = s0; e < s1; ++e) {
                int jj = esrc[e];
                if ((unsigned)jj < (unsigned)N)
                    acc += x[(long)jj * D + j];
            }
            hrow[half][j] = acc;
        }
        __syncthreads();
        if (valid) {
            const float4* hp = (const float4*)hrow[half];
            float a0 = 0.f, a1 = 0.f, a2 = 0.f, a3 = 0.f;
            #pragma unroll
            for (int q = 0; q < 8; ++q) {
                float4 hA = hp[4*q+0], hB = hp[4*q+1], hC = hp[4*q+2], hD = hp[4*q+3];
                a0 = fmaf(hA.x, w[16*q+ 0], a0); a0 = fmaf(hA.y, w[16*q+ 1], a0);
                a0 = fmaf(hA.z, w[16*q+ 2], a0); a0 = fmaf(hA.w, w[16*q+ 3], a0);
                a1 = fmaf(hB.x, w[16*q+ 4], a1); a1 = fmaf(hB.y, w[16*q+ 5], a1);
                a1 = fmaf(hB.z, w[16*q+ 6], a1); a1 = fmaf(hB.w, w[16*q+ 7], a1);
                a2 = fmaf(hC.x, w[16*q+ 8], a2); a2 = fmaf(hC.y, w[16*q+ 9], a2);
                a2 = fmaf(hC.z, w[16*q+10], a2); a2 = fmaf(hC.w, w[16*q+11], a2);
                a3 = fmaf(hD.x, w[16*q+12], a3); a3 = fmaf(hD.y, w[16*q+13], a3);
                a3 = fmaf(hD.z, w[16*q+14], a3); a3 = fmaf(hD.w, w[16*q+15], a3);
            }
            float acc = bj + ((a0 + a1) + (a2 + a3));
            hlin[(long)i * D + j] = acc;
            psum += acc;
            psq  = fmaf(acc, acc, psq);
        }
        __syncthreads();
    }

    red[tid] = psum;
    __syncthreads();
    float s2 = (tid < 128) ? (red[tid] + red[tid + 128]) : 0.0f;
    __syncthreads();
    red[tid] = psq;
    __syncthreads();
    if (tid < 128) {
        unsafeAtomicAdd(&stats[j],       s2);
        unsafeAtomicAdd(&stats[128 + j], red[tid] + red[tid + 128]);
    }
}

// ---------------------------------------------------------------------------
// Finalize BN: stats [0..127]=sum [128..255]=sumsq -> [256..383]=ginv [384..]=shift
// ---------------------------------------------------------------------------
__global__ void finalize_kernel(const float* __restrict__ gamma,
                                const float* __restrict__ beta,
                                float* __restrict__ stats, float invN)
{
    int j = threadIdx.x;  // 0..127
    float mean = stats[j] * invN;
    float var  = stats[128 + j] * invN - mean * mean;
    float ginv = gamma[j] * rsqrtf(var + 1e-5f);
    stats[256 + j] = ginv;
    stats[384 + j] = beta[j] - mean * ginv;
}

// ---------------------------------------------------------------------------
// Epilogue: out = relu(hlin*ginv + shift) + x.  hlin aliases dout with the
// SAME float2 index per thread (read pair t, write pair t) -> race-free.
// NO __restrict__ on the aliasing pair.
// ---------------------------------------------------------------------------
__global__ __launch_bounds__(256) void out_kernel(
    const float2* hlin2, const float2* __restrict__ x2,
    const float* __restrict__ stats, float2* dout, long total)
{
    __shared__ float ginv[D], sh[D];
    if (threadIdx.x < D) {
        ginv[threadIdx.x] = stats[256 + threadIdx.x];
        sh[threadIdx.x]   = stats[384 + threadIdx.x];
    }
    __syncthreads();
    long t = (long)blockIdx.x * 256 + threadIdx.x;
    if (t >= total) return;
    int f = (int)(t & 63);
    float2 hv = hlin2[t];
    float2 xv = x2[t];
    float v0 = fmaf(hv.x, ginv[2 * f],     sh[2 * f]);
    float v1 = fmaf(hv.y, ginv[2 * f + 1], sh[2 * f + 1]);
    v0 = fmaxf(v0, 0.0f) + xv.x;
    v1 = fmaxf(v1, 0.0f) + xv.y;
    dout[t] = make_float2(v0, v1);
}

// ---------------------------------------------------------------------------
static inline size_t align16(size_t v) { return (v + 15) & ~(size_t)15; }

extern "C" void kernel_launch(void* const* d_in, const int* in_sizes, int n_in,
                              void* d_out, int out_size, void* d_ws, size_t ws_size,
                              hipStream_t stream)
{
    const float* x     = (const float*)d_in[0];
    const int*   ei    = (const int*)d_in[1];
    const float* W     = (const float*)d_in[2];
    const float* b     = (const float*)d_in[3];
    const float* gamma = (const float*)d_in[4];
    const float* beta  = (const float*)d_in[5];
    const float* geps  = (const float*)d_in[6];

    const int N = in_sizes[0] / D;
    const int E = in_sizes[1] / 2;
    const int* src = ei;        // edge_index[0,:]
    const int* dst = ei + E;    // edge_index[1,:]

    // ws layout (~3 MB): [stats 512f][cnt N] (both zeroed) [rowptr N+1][cursor N][esrc E]
    char* ws = (char*)d_ws;
    size_t off = 0;
    float* stats  = (float*)(ws + off); off += 2048;
    int*   cnt    = (int*)  (ws + off); off += align16((size_t)N * 4);
    size_t zero_bytes = off;
    int*   rowptr = (int*)  (ws + off); off += align16((size_t)(N + 1) * 4);
    int*   cursor = (int*)  (ws + off); off += align16((size_t)N * 4);
    int*   esrc   = (int*)  (ws + off); off += align16((size_t)E * 4);

    // hlin stages in d_out (fp32, same element count; same-index alias in out_kernel)
    float* hlin = (float*)d_out;

    hipMemsetAsync(stats, 0, zero_bytes, stream);

    count_kernel<<<(E + 255) / 256, 256, 0, stream>>>(dst, cnt, E, N);
    scan_kernel<<<1, 256, 0, stream>>>(cnt, rowptr, cursor, N);
    fill_kernel<<<(E + 255) / 256, 256, 0, stream>>>(src, dst, cursor, esrc, E, N);

    gemm_gather_stats_kernel<<<(N + 127) / 128, 256, 0, stream>>>(
        x, rowptr, esrc, W, b, geps, hlin, stats, N, E);

    finalize_kernel<<<1, 128, 0, stream>>>(gamma, beta, stats, 1.0f / (float)N);

    long ototal = (long)N * DH;
    out_kernel<<<(int)((ototal + 255) / 256), 256, 0, stream>>>(
        (const float2*)d_out, (const float2*)x, stats, (float2*)d_out, ototal);
}

// Round 8
// 375.135 us; speedup vs baseline: 2.3984x; 2.3984x over previous
//
#include <hip/hip_runtime.h>

#define D 128
#define DH 64  // D/2 (float2 pairs)

// ---------------------------------------------------------------------------
// CSR build: count -> scan (256 threads) -> fill (all bounds-checked)
// ---------------------------------------------------------------------------
__global__ __launch_bounds__(256) void count_kernel(
    const int* __restrict__ dst, int* __restrict__ cnt, int E, int N)
{
    int e = blockIdx.x * 256 + threadIdx.x;
    if (e >= E) return;
    int d = dst[e];
    if ((unsigned)d < (unsigned)N) atomicAdd(&cnt[d], 1);
}

__global__ __launch_bounds__(256) void scan_kernel(
    const int* __restrict__ cnt, int* __restrict__ rowptr,
    int* __restrict__ cursor, int N)
{
    __shared__ int lds[256];
    const int t  = threadIdx.x;
    const int CH = (N + 255) / 256;
    const int start = min(t * CH, N);
    const int end   = min(start + CH, N);
    int s = 0;
    for (int k = start; k < end; ++k) s += cnt[k];
    lds[t] = s;
    __syncthreads();
    for (int off = 1; off < 256; off <<= 1) {
        int v = (t >= off) ? lds[t - off] : 0;
        __syncthreads();
        lds[t] += v;
        __syncthreads();
    }
    int run = lds[t] - s;   // exclusive prefix of this chunk
    for (int k = start; k < end; ++k) {
        rowptr[k] = run; cursor[k] = run; run += cnt[k];
    }
    if (t == 255) rowptr[N] = lds[255];
}

__global__ __launch_bounds__(256) void fill_kernel(
    const int* __restrict__ src, const int* __restrict__ dst,
    int* __restrict__ cursor, int* __restrict__ esrc, int E, int N)
{
    int e = blockIdx.x * 256 + threadIdx.x;
    if (e >= E) return;
    int d = dst[e];
    if ((unsigned)d >= (unsigned)N) return;
    int p = atomicAdd(&cursor[d], 1);
    if ((unsigned)p < (unsigned)E) esrc[p] = src[e];
}

// ---------------------------------------------------------------------------
// Gather: ONE WAVE PER NODE (massive TLP to hide the pointer-chase).
// h[i] = (1+eps)*x[i] + sum_{j in nbr(i)} x[j], lane = float2 slot of the row.
// Edge loop unrolled x4 -> 4 independent row-loads in flight per wave.
// h is written fp32 into d_out (overwritten later by hlin then out, in order).
// ---------------------------------------------------------------------------
__global__ __launch_bounds__(256) void gather_kernel(
    const float2* __restrict__ x2, const int* __restrict__ rowptr,
    const int* __restrict__ esrc, const float* __restrict__ geps,
    float2* __restrict__ h2, int N, int E)
{
    const float eps1 = 1.0f + geps[0];
    const int node = blockIdx.x * 4 + (threadIdx.x >> 6);
    const int lane = threadIdx.x & 63;
    if (node >= N) return;
    int s0 = rowptr[node];
    int s1 = rowptr[node + 1];
    s0 = max(0, min(s0, E));       // any CSR bug stays finite
    s1 = max(s0, min(s1, E));
    float2 xv = x2[(long)node * DH + lane];
    float ax = xv.x * eps1, ay = xv.y * eps1;
    int e = s0;
    for (; e + 3 < s1; e += 4) {
        int j0 = esrc[e], j1 = esrc[e + 1], j2 = esrc[e + 2], j3 = esrc[e + 3];
        if ((unsigned)j0 < (unsigned)N) { float2 v = x2[(long)j0 * DH + lane]; ax += v.x; ay += v.y; }
        if ((unsigned)j1 < (unsigned)N) { float2 v = x2[(long)j1 * DH + lane]; ax += v.x; ay += v.y; }
        if ((unsigned)j2 < (unsigned)N) { float2 v = x2[(long)j2 * DH + lane]; ax += v.x; ay += v.y; }
        if ((unsigned)j3 < (unsigned)N) { float2 v = x2[(long)j3 * DH + lane]; ax += v.x; ay += v.y; }
    }
    for (; e < s1; ++e) {
        int j = esrc[e];
        if ((unsigned)j < (unsigned)N) { float2 v = x2[(long)j * DH + lane]; ax += v.x; ay += v.y; }
    }
    h2[(long)node * DH + lane] = make_float2(ax, ay);
}

// ---------------------------------------------------------------------------
// GEMM + BN stats: hlin = h @ W^T + b (fp32) + col sum/sumsq.
// 64 rows per block -> 625 blocks. h is read from d_out and hlin written back
// IN-PLACE (row i write ordered after row i read by this block's barriers;
// rows are block-private). NO __restrict__ on the h/hlin alias.
// ---------------------------------------------------------------------------
__global__ __launch_bounds__(256) void gemm_stats_kernel(
    const float* h, const float* __restrict__ W,
    const float* __restrict__ bb, float* hlin,
    float* __restrict__ stats, int N)
{
    __shared__ __align__(16) float hrow[2][D];
    __shared__ float red[256];

    const int tid  = threadIdx.x;
    const int j    = tid & (D - 1);
    const int half = tid >> 7;

    // W row j -> 128 VGPRs
    float w[D];
    {
        const float4* Wq = (const float4*)(W + j * D);
        #pragma unroll
        for (int q = 0; q < 32; ++q) {
            float4 u = Wq[q];
            w[4*q+0] = u.x; w[4*q+1] = u.y; w[4*q+2] = u.z; w[4*q+3] = u.w;
        }
    }
    const float bj = bb[j];

    float psum = 0.0f, psq = 0.0f;
    const int row0 = blockIdx.x * 64;

    for (int it = 0; it < 32; ++it) {
        const int i = row0 + it * 2 + half;
        const bool valid = (i < N);
        if (valid) hrow[half][j] = h[(long)i * D + j];
        __syncthreads();
        if (valid) {
            const float4* hp = (const float4*)hrow[half];
            float a0 = 0.f, a1 = 0.f, a2 = 0.f, a3 = 0.f;
            #pragma unroll
            for (int q = 0; q < 8; ++q) {
                float4 hA = hp[4*q+0], hB = hp[4*q+1], hC = hp[4*q+2], hD = hp[4*q+3];
                a0 = fmaf(hA.x, w[16*q+ 0], a0); a0 = fmaf(hA.y, w[16*q+ 1], a0);
                a0 = fmaf(hA.z, w[16*q+ 2], a0); a0 = fmaf(hA.w, w[16*q+ 3], a0);
                a1 = fmaf(hB.x, w[16*q+ 4], a1); a1 = fmaf(hB.y, w[16*q+ 5], a1);
                a1 = fmaf(hB.z, w[16*q+ 6], a1); a1 = fmaf(hB.w, w[16*q+ 7], a1);
                a2 = fmaf(hC.x, w[16*q+ 8], a2); a2 = fmaf(hC.y, w[16*q+ 9], a2);
                a2 = fmaf(hC.z, w[16*q+10], a2); a2 = fmaf(hC.w, w[16*q+11], a2);
                a3 = fmaf(hD.x, w[16*q+12], a3); a3 = fmaf(hD.y, w[16*q+13], a3);
                a3 = fmaf(hD.z, w[16*q+14], a3); a3 = fmaf(hD.w, w[16*q+15], a3);
            }
            float acc = bj + ((a0 + a1) + (a2 + a3));
            hlin[(long)i * D + j] = acc;
            psum += acc;
            psq  = fmaf(acc, acc, psq);
        }
        __syncthreads();
    }

    red[tid] = psum;
    __syncthreads();
    float s2 = (tid < 128) ? (red[tid] + red[tid + 128]) : 0.0f;
    __syncthreads();
    red[tid] = psq;
    __syncthreads();
    if (tid < 128) {
        unsafeAtomicAdd(&stats[j],       s2);
        unsafeAtomicAdd(&stats[128 + j], red[tid] + red[tid + 128]);
    }
}

// ---------------------------------------------------------------------------
// Finalize BN: stats [0..127]=sum [128..255]=sumsq -> [256..383]=ginv [384..]=shift
// ---------------------------------------------------------------------------
__global__ void finalize_kernel(const float* __restrict__ gamma,
                                const float* __restrict__ beta,
                                float* __restrict__ stats, float invN)
{
    int j = threadIdx.x;  // 0..127
    float mean = stats[j] * invN;
    float var  = stats[128 + j] * invN - mean * mean;
    float ginv = gamma[j] * rsqrtf(var + 1e-5f);
    stats[256 + j] = ginv;
    stats[384 + j] = beta[j] - mean * ginv;
}

// ---------------------------------------------------------------------------
// Epilogue: out = relu(hlin*ginv + shift) + x. Same-index float2 alias
// (read pair t, write pair t) -> race-free. NO __restrict__ on the alias.
// ---------------------------------------------------------------------------
__global__ __launch_bounds__(256) void out_kernel(
    const float2* hlin2, const float2* __restrict__ x2,
    const float* __restrict__ stats, float2* dout, long total)
{
    __shared__ float ginv[D], sh[D];
    if (threadIdx.x < D) {
        ginv[threadIdx.x] = stats[256 + threadIdx.x];
        sh[threadIdx.x]   = stats[384 + threadIdx.x];
    }
    __syncthreads();
    long t = (long)blockIdx.x * 256 + threadIdx.x;
    if (t >= total) return;
    int f = (int)(t & 63);
    float2 hv = hlin2[t];
    float2 xv = x2[t];
    float v0 = fmaf(hv.x, ginv[2 * f],     sh[2 * f]);
    float v1 = fmaf(hv.y, ginv[2 * f + 1], sh[2 * f + 1]);
    v0 = fmaxf(v0, 0.0f) + xv.x;
    v1 = fmaxf(v1, 0.0f) + xv.y;
    dout[t] = make_float2(v0, v1);
}

// ---------------------------------------------------------------------------
static inline size_t align16(size_t v) { return (v + 15) & ~(size_t)15; }

extern "C" void kernel_launch(void* const* d_in, const int* in_sizes, int n_in,
                              void* d_out, int out_size, void* d_ws, size_t ws_size,
                              hipStream_t stream)
{
    const float* x     = (const float*)d_in[0];
    const int*   ei    = (const int*)d_in[1];
    const float* W     = (const float*)d_in[2];
    const float* b     = (const float*)d_in[3];
    const float* gamma = (const float*)d_in[4];
    const float* beta  = (const float*)d_in[5];
    const float* geps  = (const float*)d_in[6];

    const int N = in_sizes[0] / D;
    const int E = in_sizes[1] / 2;
    const int* src = ei;        // edge_index[0,:]
    const int* dst = ei + E;    // edge_index[1,:]

    // ws layout (~3 MB): [stats 512f][cnt N] (both zeroed) [rowptr N+1][cursor N][esrc E]
    char* ws = (char*)d_ws;
    size_t off = 0;
    float* stats  = (float*)(ws + off); off += 2048;
    int*   cnt    = (int*)  (ws + off); off += align16((size_t)N * 4);
    size_t zero_bytes = off;
    int*   rowptr = (int*)  (ws + off); off += align16((size_t)(N + 1) * 4);
    int*   cursor = (int*)  (ws + off); off += align16((size_t)N * 4);
    int*   esrc   = (int*)  (ws + off); off += align16((size_t)E * 4);

    hipMemsetAsync(stats, 0, zero_bytes, stream);

    count_kernel<<<(E + 255) / 256, 256, 0, stream>>>(dst, cnt, E, N);
    scan_kernel<<<1, 256, 0, stream>>>(cnt, rowptr, cursor, N);
    fill_kernel<<<(E + 255) / 256, 256, 0, stream>>>(src, dst, cursor, esrc, E, N);

    // h -> d_out (fp32), then hlin in-place, then out in-place: all ordered.
    gather_kernel<<<(N + 3) / 4, 256, 0, stream>>>(
        (const float2*)x, rowptr, esrc, geps, (float2*)d_out, N, E);

    gemm_stats_kernel<<<(N + 63) / 64, 256, 0, stream>>>(
        (const float*)d_out, W, b, (float*)d_out, stats, N);

    finalize_kernel<<<1, 128, 0, stream>>>(gamma, beta, stats, 1.0f / (float)N);

    long ototal = (long)N * DH;
    out_kernel<<<(int)((ototal + 255) / 256), 256, 0, stream>>>(
        (const float2*)d_out, (const float2*)x, stats, (float2*)d_out, ototal);
}

// Round 9
// 297.194 us; speedup vs baseline: 3.0274x; 1.2623x over previous
//
#include <hip/hip_runtime.h>

#define D 128
#define DH 64  // D/2 (float2 pairs)

// ---------------------------------------------------------------------------
// CSR build: count -> multiblock scan (A/B/C) -> fill (all bounds-checked)
// ---------------------------------------------------------------------------
__global__ __launch_bounds__(256) void count_kernel(
    const int* __restrict__ dst, int* __restrict__ cnt, int E, int N)
{
    int e = blockIdx.x * 256 + threadIdx.x;
    if (e >= E) return;
    int d = dst[e];
    if ((unsigned)d < (unsigned)N) atomicAdd(&cnt[d], 1);
}

// A: per-block (1024-element chunk) sums
__global__ __launch_bounds__(256) void blocksum_kernel(
    const int* __restrict__ cnt, int* __restrict__ bsum, int N)
{
    __shared__ int lds[256];
    const int base = blockIdx.x * 1024;
    const int t = threadIdx.x;
    int s = 0;
    #pragma unroll
    for (int p = 0; p < 4; ++p) {
        int k = base + p * 256 + t;
        if (k < N) s += cnt[k];
    }
    lds[t] = s;
    __syncthreads();
    for (int off = 128; off > 0; off >>= 1) {
        if (t < off) lds[t] += lds[t + off];
        __syncthreads();
    }
    if (t == 0) bsum[blockIdx.x] = lds[0];
}

// B: scan the block sums (NB <= 256) -> exclusive offsets; write rowptr[N]=total
__global__ __launch_bounds__(256) void scanbsum_kernel(
    int* __restrict__ bsum, int* __restrict__ rowptrN, int NB)
{
    __shared__ int lds[256];
    const int t = threadIdx.x;
    int v = (t < NB) ? bsum[t] : 0;
    lds[t] = v;
    __syncthreads();
    for (int off = 1; off < 256; off <<= 1) {
        int u = (t >= off) ? lds[t - off] : 0;
        __syncthreads();
        lds[t] += u;
        __syncthreads();
    }
    if (t < NB) bsum[t] = lds[t] - v;   // exclusive block offset
    if (t == 255) *rowptrN = lds[255];  // grand total
}

// C: per-chunk exclusive scan + block offset -> rowptr & cursor
__global__ __launch_bounds__(256) void scanwrite_kernel(
    const int* __restrict__ cnt, const int* __restrict__ bsum,
    int* __restrict__ rowptr, int* __restrict__ cursor, int N)
{
    __shared__ int lds[256];
    const int base = blockIdx.x * 1024;
    const int t = threadIdx.x;
    int offset = bsum[blockIdx.x];
    #pragma unroll
    for (int p = 0; p < 4; ++p) {
        int k = base + p * 256 + t;
        int v = (k < N) ? cnt[k] : 0;
        lds[t] = v;
        __syncthreads();
        for (int off = 1; off < 256; off <<= 1) {
            int u = (t >= off) ? lds[t - off] : 0;
            __syncthreads();
            lds[t] += u;
            __syncthreads();
        }
        int excl = offset + lds[t] - v;
        if (k < N) { rowptr[k] = excl; cursor[k] = excl; }
        offset += lds[255];
        __syncthreads();
    }
}

__global__ __launch_bounds__(256) void fill_kernel(
    const int* __restrict__ src, const int* __restrict__ dst,
    int* __restrict__ cursor, int* __restrict__ esrc, int E, int N)
{
    int e = blockIdx.x * 256 + threadIdx.x;
    if (e >= E) return;
    int d = dst[e];
    if ((unsigned)d >= (unsigned)N) return;
    int p = atomicAdd(&cursor[d], 1);
    if ((unsigned)p < (unsigned)E) esrc[p] = src[e];
}

// ---------------------------------------------------------------------------
// Gather: one wave per node. h[i] = (1+eps)*x[i] + sum_{j in nbr(i)} x[j].
// Edge loop unrolled x4 -> 4 independent row-loads in flight per wave.
// h written fp32 into d_out (overwritten later by hlin then out, in order).
// ---------------------------------------------------------------------------
__global__ __launch_bounds__(256) void gather_kernel(
    const float2* __restrict__ x2, const int* __restrict__ rowptr,
    const int* __restrict__ esrc, const float* __restrict__ geps,
    float2* __restrict__ h2, int N, int E)
{
    const float eps1 = 1.0f + geps[0];
    const int node = blockIdx.x * 4 + (threadIdx.x >> 6);
    const int lane = threadIdx.x & 63;
    if (node >= N) return;
    int s0 = rowptr[node];
    int s1 = rowptr[node + 1];
    s0 = max(0, min(s0, E));       // any CSR bug stays finite
    s1 = max(s0, min(s1, E));
    float2 xv = x2[(long)node * DH + lane];
    float ax = xv.x * eps1, ay = xv.y * eps1;
    int e = s0;
    for (; e + 3 < s1; e += 4) {
        int j0 = esrc[e], j1 = esrc[e + 1], j2 = esrc[e + 2], j3 = esrc[e + 3];
        if ((unsigned)j0 < (unsigned)N) { float2 v = x2[(long)j0 * DH + lane]; ax += v.x; ay += v.y; }
        if ((unsigned)j1 < (unsigned)N) { float2 v = x2[(long)j1 * DH + lane]; ax += v.x; ay += v.y; }
        if ((unsigned)j2 < (unsigned)N) { float2 v = x2[(long)j2 * DH + lane]; ax += v.x; ay += v.y; }
        if ((unsigned)j3 < (unsigned)N) { float2 v = x2[(long)j3 * DH + lane]; ax += v.x; ay += v.y; }
    }
    for (; e < s1; ++e) {
        int j = esrc[e];
        if ((unsigned)j < (unsigned)N) { float2 v = x2[(long)j * DH + lane]; ax += v.x; ay += v.y; }
    }
    h2[(long)node * DH + lane] = make_float2(ax, ay);
}

// ---------------------------------------------------------------------------
// GEMM + BN stats: hlin = h @ W^T + b (fp32) + col sum/sumsq.
// 64 rows per block -> 625 blocks. h read from d_out, hlin written IN-PLACE
// (row i write ordered after row i read by this block's barriers).
// NO __restrict__ on the h/hlin alias.
// ---------------------------------------------------------------------------
__global__ __launch_bounds__(256) void gemm_stats_kernel(
    const float* h, const float* __restrict__ W,
    const float* __restrict__ bb, float* hlin,
    float* __restrict__ stats, int N)
{
    __shared__ __align__(16) float hrow[2][D];
    __shared__ float red[256];

    const int tid  = threadIdx.x;
    const int j    = tid & (D - 1);
    const int half = tid >> 7;

    float w[D];
    {
        const float4* Wq = (const float4*)(W + j * D);
        #pragma unroll
        for (int q = 0; q < 32; ++q) {
            float4 u = Wq[q];
            w[4*q+0] = u.x; w[4*q+1] = u.y; w[4*q+2] = u.z; w[4*q+3] = u.w;
        }
    }
    const float bj = bb[j];

    float psum = 0.0f, psq = 0.0f;
    const int row0 = blockIdx.x * 64;

    for (int it = 0; it < 32; ++it) {
        const int i = row0 + it * 2 + half;
        const bool valid = (i < N);
        if (valid) hrow[half][j] = h[(long)i * D + j];
        __syncthreads();
        if (valid) {
            const float4* hp = (const float4*)hrow[half];
            float a0 = 0.f, a1 = 0.f, a2 = 0.f, a3 = 0.f;
            #pragma unroll
            for (int q = 0; q < 8; ++q) {
                float4 hA = hp[4*q+0], hB = hp[4*q+1], hC = hp[4*q+2], hD = hp[4*q+3];
                a0 = fmaf(hA.x, w[16*q+ 0], a0); a0 = fmaf(hA.y, w[16*q+ 1], a0);
                a0 = fmaf(hA.z, w[16*q+ 2], a0); a0 = fmaf(hA.w, w[16*q+ 3], a0);
                a1 = fmaf(hB.x, w[16*q+ 4], a1); a1 = fmaf(hB.y, w[16*q+ 5], a1);
                a1 = fmaf(hB.z, w[16*q+ 6], a1); a1 = fmaf(hB.w, w[16*q+ 7], a1);
                a2 = fmaf(hC.x, w[16*q+ 8], a2); a2 = fmaf(hC.y, w[16*q+ 9], a2);
                a2 = fmaf(hC.z, w[16*q+10], a2); a2 = fmaf(hC.w, w[16*q+11], a2);
                a3 = fmaf(hD.x, w[16*q+12], a3); a3 = fmaf(hD.y, w[16*q+13], a3);
                a3 = fmaf(hD.z, w[16*q+14], a3); a3 = fmaf(hD.w, w[16*q+15], a3);
            }
            float acc = bj + ((a0 + a1) + (a2 + a3));
            hlin[(long)i * D + j] = acc;
            psum += acc;
            psq  = fmaf(acc, acc, psq);
        }
        __syncthreads();
    }

    red[tid] = psum;
    __syncthreads();
    float s2 = (tid < 128) ? (red[tid] + red[tid + 128]) : 0.0f;
    __syncthreads();
    red[tid] = psq;
    __syncthreads();
    if (tid < 128) {
        unsafeAtomicAdd(&stats[j],       s2);
        unsafeAtomicAdd(&stats[128 + j], red[tid] + red[tid + 128]);
    }
}

// ---------------------------------------------------------------------------
// Finalize BN: stats [0..127]=sum [128..255]=sumsq -> [256..383]=ginv [384..]=shift
// ---------------------------------------------------------------------------
__global__ void finalize_kernel(const float* __restrict__ gamma,
                                const float* __restrict__ beta,
                                float* __restrict__ stats, float invN)
{
    int j = threadIdx.x;  // 0..127
    float mean = stats[j] * invN;
    float var  = stats[128 + j] * invN - mean * mean;
    float ginv = gamma[j] * rsqrtf(var + 1e-5f);
    stats[256 + j] = ginv;
    stats[384 + j] = beta[j] - mean * ginv;
}

// ---------------------------------------------------------------------------
// Epilogue: out = relu(hlin*ginv + shift) + x. Same-index float2 alias
// (read pair t, write pair t) -> race-free. NO __restrict__ on the alias.
// ---------------------------------------------------------------------------
__global__ __launch_bounds__(256) void out_kernel(
    const float2* hlin2, const float2* __restrict__ x2,
    const float* __restrict__ stats, float2* dout, long total)
{
    __shared__ float ginv[D], sh[D];
    if (threadIdx.x < D) {
        ginv[threadIdx.x] = stats[256 + threadIdx.x];
        sh[threadIdx.x]   = stats[384 + threadIdx.x];
    }
    __syncthreads();
    long t = (long)blockIdx.x * 256 + threadIdx.x;
    if (t >= total) return;
    int f = (int)(t & 63);
    float2 hv = hlin2[t];
    float2 xv = x2[t];
    float v0 = fmaf(hv.x, ginv[2 * f],     sh[2 * f]);
    float v1 = fmaf(hv.y, ginv[2 * f + 1], sh[2 * f + 1]);
    v0 = fmaxf(v0, 0.0f) + xv.x;
    v1 = fmaxf(v1, 0.0f) + xv.y;
    dout[t] = make_float2(v0, v1);
}

// ---------------------------------------------------------------------------
static inline size_t align16(size_t v) { return (v + 15) & ~(size_t)15; }

extern "C" void kernel_launch(void* const* d_in, const int* in_sizes, int n_in,
                              void* d_out, int out_size, void* d_ws, size_t ws_size,
                              hipStream_t stream)
{
    const float* x     = (const float*)d_in[0];
    const int*   ei    = (const int*)d_in[1];
    const float* W     = (const float*)d_in[2];
    const float* b     = (const float*)d_in[3];
    const float* gamma = (const float*)d_in[4];
    const float* beta  = (const float*)d_in[5];
    const float* geps  = (const float*)d_in[6];

    const int N = in_sizes[0] / D;
    const int E = in_sizes[1] / 2;
    const int* src = ei;        // edge_index[0,:]
    const int* dst = ei + E;    // edge_index[1,:]

    const int NB = (N + 1023) / 1024;   // scan chunks (40 for N=40000; <=256 ok)

    // ws layout (~3 MB): [stats 512f][cnt N] (zeroed) [rowptr N+1][cursor N][bsum NB][esrc E]
    char* ws = (char*)d_ws;
    size_t off = 0;
    float* stats  = (float*)(ws + off); off += 2048;
    int*   cnt    = (int*)  (ws + off); off += align16((size_t)N * 4);
    size_t zero_bytes = off;
    int*   rowptr = (int*)  (ws + off); off += align16((size_t)(N + 1) * 4);
    int*   cursor = (int*)  (ws + off); off += align16((size_t)N * 4);
    int*   bsum   = (int*)  (ws + off); off += align16((size_t)NB * 4);
    int*   esrc   = (int*)  (ws + off); off += align16((size_t)E * 4);

    hipMemsetAsync(stats, 0, zero_bytes, stream);

    count_kernel<<<(E + 255) / 256, 256, 0, stream>>>(dst, cnt, E, N);
    blocksum_kernel<<<NB, 256, 0, stream>>>(cnt, bsum, N);
    scanbsum_kernel<<<1, 256, 0, stream>>>(bsum, rowptr + N, NB);
    scanwrite_kernel<<<NB, 256, 0, stream>>>(cnt, bsum, rowptr, cursor, N);
    fill_kernel<<<(E + 255) / 256, 256, 0, stream>>>(src, dst, cursor, esrc, E, N);

    // h -> d_out (fp32), then hlin in-place, then out in-place: all ordered.
    gather_kernel<<<(N + 3) / 4, 256, 0, stream>>>(
        (const float2*)x, rowptr, esrc, geps, (float2*)d_out, N, E);

    gemm_stats_kernel<<<(N + 63) / 64, 256, 0, stream>>>(
        (const float*)d_out, W, b, (float*)d_out, stats, N);

    finalize_kernel<<<1, 128, 0, stream>>>(gamma, beta, stats, 1.0f / (float)N);

    long ototal = (long)N * DH;
    out_kernel<<<(int)((ototal + 255) / 256), 256, 0, stream>>>(
        (const float2*)d_out, (const float2*)x, stats, (float2*)d_out, ototal);
}

// Round 10
// 245.233 us; speedup vs baseline: 3.6689x; 1.2119x over previous
//
#include <hip/hip_runtime.h>

#define D 128
#define DH 64  // D/2 (float2 pairs)
#define KC 32  // GEMM k-chunk

// ---------------------------------------------------------------------------
// CSR build: count -> multiblock scan (A/B/C) -> fill (all bounds-checked)
// ---------------------------------------------------------------------------
__global__ __launch_bounds__(256) void count_kernel(
    const int* __restrict__ dst, int* __restrict__ cnt, int E, int N)
{
    int e = blockIdx.x * 256 + threadIdx.x;
    if (e >= E) return;
    int d = dst[e];
    if ((unsigned)d < (unsigned)N) atomicAdd(&cnt[d], 1);
}

__global__ __launch_bounds__(256) void blocksum_kernel(
    const int* __restrict__ cnt, int* __restrict__ bsum, int N)
{
    __shared__ int lds[256];
    const int base = blockIdx.x * 1024;
    const int t = threadIdx.x;
    int s = 0;
    #pragma unroll
    for (int p = 0; p < 4; ++p) {
        int k = base + p * 256 + t;
        if (k < N) s += cnt[k];
    }
    lds[t] = s;
    __syncthreads();
    for (int off = 128; off > 0; off >>= 1) {
        if (t < off) lds[t] += lds[t + off];
        __syncthreads();
    }
    if (t == 0) bsum[blockIdx.x] = lds[0];
}

__global__ __launch_bounds__(256) void scanbsum_kernel(
    int* __restrict__ bsum, int* __restrict__ rowptrN, int NB)
{
    __shared__ int lds[256];
    const int t = threadIdx.x;
    int v = (t < NB) ? bsum[t] : 0;
    lds[t] = v;
    __syncthreads();
    for (int off = 1; off < 256; off <<= 1) {
        int u = (t >= off) ? lds[t - off] : 0;
        __syncthreads();
        lds[t] += u;
        __syncthreads();
    }
    if (t < NB) bsum[t] = lds[t] - v;   // exclusive block offset
    if (t == 255) *rowptrN = lds[255];  // grand total
}

__global__ __launch_bounds__(256) void scanwrite_kernel(
    const int* __restrict__ cnt, const int* __restrict__ bsum,
    int* __restrict__ rowptr, int* __restrict__ cursor, int N)
{
    __shared__ int lds[256];
    const int base = blockIdx.x * 1024;
    const int t = threadIdx.x;
    int offset = bsum[blockIdx.x];
    #pragma unroll
    for (int p = 0; p < 4; ++p) {
        int k = base + p * 256 + t;
        int v = (k < N) ? cnt[k] : 0;
        lds[t] = v;
        __syncthreads();
        for (int off = 1; off < 256; off <<= 1) {
            int u = (t >= off) ? lds[t - off] : 0;
            __syncthreads();
            lds[t] += u;
            __syncthreads();
        }
        int excl = offset + lds[t] - v;
        if (k < N) { rowptr[k] = excl; cursor[k] = excl; }
        offset += lds[255];
        __syncthreads();
    }
}

__global__ __launch_bounds__(256) void fill_kernel(
    const int* __restrict__ src, const int* __restrict__ dst,
    int* __restrict__ cursor, int* __restrict__ esrc, int E, int N)
{
    int e = blockIdx.x * 256 + threadIdx.x;
    if (e >= E) return;
    int d = dst[e];
    if ((unsigned)d >= (unsigned)N) return;
    int p = atomicAdd(&cursor[d], 1);
    if ((unsigned)p < (unsigned)E) esrc[p] = src[e];
}

// ---------------------------------------------------------------------------
// Gather: half-wave (32 lanes, float4) per node -> 2 nodes per wave.
// h[i] = (1+eps)*x[i] + sum_{j in nbr(i)} x[j]; unrolled x4 for ILP.
// h written fp32 into d_out (overwritten later by hlin then out, in order).
// ---------------------------------------------------------------------------
__global__ __launch_bounds__(256) void gather_kernel(
    const float4* __restrict__ x4, const int* __restrict__ rowptr,
    const int* __restrict__ esrc, const float* __restrict__ geps,
    float4* __restrict__ h4, int N, int E)
{
    const float eps1 = 1.0f + geps[0];
    const int node = blockIdx.x * 8 + (threadIdx.x >> 5);
    const int lane = threadIdx.x & 31;       // 32 float4 slots per row
    if (node >= N) return;
    int s0 = rowptr[node];
    int s1 = rowptr[node + 1];
    s0 = max(0, min(s0, E));       // any CSR bug stays finite
    s1 = max(s0, min(s1, E));
    float4 a = x4[(long)node * 32 + lane];
    a.x *= eps1; a.y *= eps1; a.z *= eps1; a.w *= eps1;
    int e = s0;
    for (; e + 3 < s1; e += 4) {
        int j0 = esrc[e], j1 = esrc[e + 1], j2 = esrc[e + 2], j3 = esrc[e + 3];
        if ((unsigned)j0 < (unsigned)N) { float4 v = x4[(long)j0 * 32 + lane]; a.x += v.x; a.y += v.y; a.z += v.z; a.w += v.w; }
        if ((unsigned)j1 < (unsigned)N) { float4 v = x4[(long)j1 * 32 + lane]; a.x += v.x; a.y += v.y; a.z += v.z; a.w += v.w; }
        if ((unsigned)j2 < (unsigned)N) { float4 v = x4[(long)j2 * 32 + lane]; a.x += v.x; a.y += v.y; a.z += v.z; a.w += v.w; }
        if ((unsigned)j3 < (unsigned)N) { float4 v = x4[(long)j3 * 32 + lane]; a.x += v.x; a.y += v.y; a.z += v.z; a.w += v.w; }
    }
    for (; e < s1; ++e) {
        int j = esrc[e];
        if ((unsigned)j < (unsigned)N) { float4 v = x4[(long)j * 32 + lane]; a.x += v.x; a.y += v.y; a.z += v.z; a.w += v.w; }
    }
    h4[(long)node * 32 + lane] = a;
}

// ---------------------------------------------------------------------------
// Register-tiled GEMM + BN stats: hlin = h @ W^T + b, col sum/sumsq.
// Block = 256 threads = 16(tx) x 16(ty); tile 64 rows x 128 cols; each thread
// owns c[4][8] (rows ty*4.., cols tx*8..). K in chunks of 32 via LDS tiles:
//   At[k][row] (A transposed, pad 68 for write conflicts, 16B-aligned rows)
//   Bs[k][col] = W[col][k]  (pad 132)
// hb is read AND written in-place (d_out): a block reads its rows fully
// before writing them; rows are block-private. Not marked __restrict__.
// ---------------------------------------------------------------------------
__global__ __launch_bounds__(256) void gemm_stats_kernel(
    float* hb, const float* __restrict__ W,
    const float* __restrict__ bb, float* __restrict__ stats, int N)
{
    __shared__ __align__(16) float At[KC][68];
    __shared__ __align__(16) float Bs[KC][132];
    __shared__ float red[16][128];

    const int tid = threadIdx.x;
    const int tx = tid & 15;
    const int ty = tid >> 4;
    const int row0 = blockIdx.x * 64;

    float c[4][8];
    #pragma unroll
    for (int r = 0; r < 4; ++r)
        #pragma unroll
        for (int cc = 0; cc < 8; ++cc) c[r][cc] = 0.0f;

    for (int k0 = 0; k0 < D; k0 += KC) {
        // stage A (64 x KC, transposed). s = q*256+tid: row=s>>3, kq=s&7 -> coalesced
        #pragma unroll
        for (int q = 0; q < 2; ++q) {
            int s = q * 256 + tid;
            int r = s >> 3;
            int kq = s & 7;
            int grow = row0 + r;
            float4 v = make_float4(0.f, 0.f, 0.f, 0.f);
            if (grow < N) v = *(const float4*)(hb + (long)grow * D + k0 + kq * 4);
            At[kq * 4 + 0][r] = v.x; At[kq * 4 + 1][r] = v.y;
            At[kq * 4 + 2][r] = v.z; At[kq * 4 + 3][r] = v.w;
        }
        // stage B (KC x 128): Bs[k][col] = W[col][k0+k]
        #pragma unroll
        for (int q = 0; q < 4; ++q) {
            int s = q * 256 + tid;
            int col = s >> 3;
            int kq = s & 7;
            float4 v = *(const float4*)(W + (long)col * D + k0 + kq * 4);
            Bs[kq * 4 + 0][col] = v.x; Bs[kq * 4 + 1][col] = v.y;
            Bs[kq * 4 + 2][col] = v.z; Bs[kq * 4 + 3][col] = v.w;
        }
        __syncthreads();
        #pragma unroll
        for (int k = 0; k < KC; ++k) {
            float4 av = *(const float4*)&At[k][ty * 4];
            float4 b0 = *(const float4*)&Bs[k][tx * 8];
            float4 b1 = *(const float4*)&Bs[k][tx * 8 + 4];
            float a[4] = {av.x, av.y, av.z, av.w};
            float b[8] = {b0.x, b0.y, b0.z, b0.w, b1.x, b1.y, b1.z, b1.w};
            #pragma unroll
            for (int r = 0; r < 4; ++r)
                #pragma unroll
                for (int cc = 0; cc < 8; ++cc)
                    c[r][cc] = fmaf(a[r], b[cc], c[r][cc]);
        }
        __syncthreads();
    }

    // bias, store hlin in-place, per-thread column partials
    float bias[8];
    #pragma unroll
    for (int cc = 0; cc < 8; ++cc) bias[cc] = bb[tx * 8 + cc];

    float psum[8], psq[8];
    #pragma unroll
    for (int cc = 0; cc < 8; ++cc) { psum[cc] = 0.f; psq[cc] = 0.f; }

    #pragma unroll
    for (int r = 0; r < 4; ++r) {
        int grow = row0 + ty * 4 + r;
        if (grow < N) {
            float v[8];
            #pragma unroll
            for (int cc = 0; cc < 8; ++cc) {
                v[cc] = c[r][cc] + bias[cc];
                psum[cc] += v[cc];
                psq[cc]  = fmaf(v[cc], v[cc], psq[cc]);
            }
            float4* dst0 = (float4*)(hb + (long)grow * D + tx * 8);
            dst0[0] = make_float4(v[0], v[1], v[2], v[3]);
            dst0[1] = make_float4(v[4], v[5], v[6], v[7]);
        }
    }

    // block reduction over ty, one atomic per column
    #pragma unroll
    for (int cc = 0; cc < 8; ++cc) red[ty][tx * 8 + cc] = psum[cc];
    __syncthreads();
    if (tid < 128) {
        float s = 0.f;
        #pragma unroll
        for (int t = 0; t < 16; ++t) s += red[t][tid];
        unsafeAtomicAdd(&stats[tid], s);
    }
    __syncthreads();
    #pragma unroll
    for (int cc = 0; cc < 8; ++cc) red[ty][tx * 8 + cc] = psq[cc];
    __syncthreads();
    if (tid < 128) {
        float s = 0.f;
        #pragma unroll
        for (int t = 0; t < 16; ++t) s += red[t][tid];
        unsafeAtomicAdd(&stats[128 + tid], s);
    }
}

// ---------------------------------------------------------------------------
// Finalize BN: stats [0..127]=sum [128..255]=sumsq -> [256..383]=ginv [384..]=shift
// ---------------------------------------------------------------------------
__global__ void finalize_kernel(const float* __restrict__ gamma,
                                const float* __restrict__ beta,
                                float* __restrict__ stats, float invN)
{
    int j = threadIdx.x;  // 0..127
    float mean = stats[j] * invN;
    float var  = stats[128 + j] * invN - mean * mean;
    float ginv = gamma[j] * rsqrtf(var + 1e-5f);
    stats[256 + j] = ginv;
    stats[384 + j] = beta[j] - mean * ginv;
}

// ---------------------------------------------------------------------------
// Epilogue: out = relu(hlin*ginv + shift) + x. Same-index float2 alias
// (read pair t, write pair t) -> race-free. NO __restrict__ on the alias.
// ---------------------------------------------------------------------------
__global__ __launch_bounds__(256) void out_kernel(
    const float2* hlin2, const float2* __restrict__ x2,
    const float* __restrict__ stats, float2* dout, long total)
{
    __shared__ float ginv[D], sh[D];
    if (threadIdx.x < D) {
        ginv[threadIdx.x] = stats[256 + threadIdx.x];
        sh[threadIdx.x]   = stats[384 + threadIdx.x];
    }
    __syncthreads();
    long t = (long)blockIdx.x * 256 + threadIdx.x;
    if (t >= total) return;
    int f = (int)(t & 63);
    float2 hv = hlin2[t];
    float2 xv = x2[t];
    float v0 = fmaf(hv.x, ginv[2 * f],     sh[2 * f]);
    float v1 = fmaf(hv.y, ginv[2 * f + 1], sh[2 * f + 1]);
    v0 = fmaxf(v0, 0.0f) + xv.x;
    v1 = fmaxf(v1, 0.0f) + xv.y;
    dout[t] = make_float2(v0, v1);
}

// ---------------------------------------------------------------------------
static inline size_t align16(size_t v) { return (v + 15) & ~(size_t)15; }

extern "C" void kernel_launch(void* const* d_in, const int* in_sizes, int n_in,
                              void* d_out, int out_size, void* d_ws, size_t ws_size,
                              hipStream_t stream)
{
    const float* x     = (const float*)d_in[0];
    const int*   ei    = (const int*)d_in[1];
    const float* W     = (const float*)d_in[2];
    const float* b     = (const float*)d_in[3];
    const float* gamma = (const float*)d_in[4];
    const float* beta  = (const float*)d_in[5];
    const float* geps  = (const float*)d_in[6];

    const int N = in_sizes[0] / D;
    const int E = in_sizes[1] / 2;
    const int* src = ei;        // edge_index[0,:]
    const int* dst = ei + E;    // edge_index[1,:]

    const int NB = (N + 1023) / 1024;   // scan chunks (40 for N=40000; <=256 ok)

    // ws layout (~3 MB): [stats 512f][cnt N] (zeroed) [rowptr N+1][cursor N][bsum NB][esrc E]
    char* ws = (char*)d_ws;
    size_t off = 0;
    float* stats  = (float*)(ws + off); off += 2048;
    int*   cnt    = (int*)  (ws + off); off += align16((size_t)N * 4);
    size_t zero_bytes = off;
    int*   rowptr = (int*)  (ws + off); off += align16((size_t)(N + 1) * 4);
    int*   cursor = (int*)  (ws + off); off += align16((size_t)N * 4);
    int*   bsum   = (int*)  (ws + off); off += align16((size_t)NB * 4);
    int*   esrc   = (int*)  (ws + off); off += align16((size_t)E * 4);

    hipMemsetAsync(stats, 0, zero_bytes, stream);

    count_kernel<<<(E + 255) / 256, 256, 0, stream>>>(dst, cnt, E, N);
    blocksum_kernel<<<NB, 256, 0, stream>>>(cnt, bsum, N);
    scanbsum_kernel<<<1, 256, 0, stream>>>(bsum, rowptr + N, NB);
    scanwrite_kernel<<<NB, 256, 0, stream>>>(cnt, bsum, rowptr, cursor, N);
    fill_kernel<<<(E + 255) / 256, 256, 0, stream>>>(src, dst, cursor, esrc, E, N);

    // h -> d_out (fp32), then hlin in-place, then out in-place: all ordered.
    gather_kernel<<<(N + 7) / 8, 256, 0, stream>>>(
        (const float4*)x, rowptr, esrc, geps, (float4*)d_out, N, E);

    gemm_stats_kernel<<<(N + 63) / 64, 256, 0, stream>>>(
        (float*)d_out, W, b, stats, N);

    finalize_kernel<<<1, 128, 0, stream>>>(gamma, beta, stats, 1.0f / (float)N);

    long ototal = (long)N * DH;
    out_kernel<<<(int)((ototal + 255) / 256), 256, 0, stream>>>(
        (const float2*)d_out, (const float2*)x, stats, (float2*)d_out, ototal);
}